// Round 4
// baseline (4265.896 us; speedup 1.0000x reference)
//
#include <hip/hip_runtime.h>
#include <hip/hip_bf16.h>

#define N_NODES 100000
#define N_EDGES 1600000
#define DD 128
#define N_GRAPHS 512
#define BN_EPS 1e-5f

#define NTILES 1563            // ceil(100000/64)
#define NCHUNK 25              // src >> 12 -> 0..24 (4096 nodes = 1 MB bf16 per chunk)
#define NBUCKETS (NTILES * NCHUNK)
#define GRID_LAYER 768         // 3 blocks/CU persistent

typedef unsigned int u32;
typedef unsigned short u16;
typedef __bf16 bf16_t;
typedef __bf16 bf16x4 __attribute__((ext_vector_type(4)));
typedef __bf16 bf16x8 __attribute__((ext_vector_type(8)));
typedef float f32x4 __attribute__((ext_vector_type(4)));

__device__ __forceinline__ float bfbits2f(u32 u) {
    union { u32 i; float f; } x; x.i = u << 16; return x.f;
}

// ---------------- utility kernels ----------------

__global__ void k_zero(float4* p, int n) {
    float4 z = make_float4(0.f, 0.f, 0.f, 0.f);
    for (int i = blockIdx.x * blockDim.x + threadIdx.x; i < n; i += gridDim.x * blockDim.x)
        p[i] = z;
}

// per-node degree + per-(tile,chunk) bucket counts
__global__ void k_hist2(const int* __restrict__ src, const int* __restrict__ dst,
                        int* __restrict__ deg, int* __restrict__ bcnt) {
    for (int e = blockIdx.x * blockDim.x + threadIdx.x; e < N_EDGES; e += gridDim.x * blockDim.x) {
        int d = dst[e];
        atomicAdd(&deg[d], 1);
        int b = (d >> 6) * NCHUNK + (src[e] >> 12);
        atomicAdd(&bcnt[b], 1);
    }
}

// single block, 1024 threads: exclusive scan of bcnt[NBUCKETS] -> boff, copy to bcur
__global__ void k_scan2(const int* __restrict__ bcnt, int* __restrict__ boff, int* __restrict__ bcur) {
    __shared__ int ps[1024];
    const int CH = 39; // ceil(39075/1024)
    int t = threadIdx.x;
    int begI = t * CH;
    int endI = begI + CH; if (endI > NBUCKETS) endI = NBUCKETS;
    int s = 0;
    for (int i = begI; i < endI; ++i) s += bcnt[i];
    ps[t] = s;
    __syncthreads();
    for (int d2 = 1; d2 < 1024; d2 <<= 1) {
        int v = (t >= d2) ? ps[t - d2] : 0;
        __syncthreads();
        ps[t] += v;
        __syncthreads();
    }
    int run = ps[t] - s;
    for (int i = begI; i < endI; ++i) {
        boff[i] = run; bcur[i] = run;
        run += bcnt[i];
    }
    if (t == 1023) boff[NBUCKETS] = ps[1023];
}

// scatter edges into bucketed layout: entry = (dst&63)<<17 | src
__global__ void k_fill2(const int* __restrict__ src, const int* __restrict__ dst,
                        int* __restrict__ bcur, u32* __restrict__ csr2) {
    for (int e = blockIdx.x * blockDim.x + threadIdx.x; e < N_EDGES; e += gridDim.x * blockDim.x) {
        int d = dst[e];
        int s = src[e];
        int b = (d >> 6) * NCHUNK + (s >> 12);
        int pos = atomicAdd(&bcur[b], 1);
        csr2[pos] = ((u32)(d & 63) << 17) | (u32)s;
    }
}

__global__ void k_cvt(const float* __restrict__ x, bf16_t* __restrict__ xb) {
    const int n4 = N_NODES * DD / 4;
    const float4* x4 = (const float4*)x;
    bf16x4* o4 = (bf16x4*)xb;
    for (int i = blockIdx.x * blockDim.x + threadIdx.x; i < n4; i += gridDim.x * blockDim.x) {
        float4 v = x4[i];
        bf16x4 o;
        o.x = (bf16_t)v.x; o.y = (bf16_t)v.y; o.z = (bf16_t)v.z; o.w = (bf16_t)v.w;
        o4[i] = o;
    }
}

// Pre-shuffle the 6 weight matrices into exact MFMA B-fragment order (bf16).
__global__ void k_shufw(const float* __restrict__ W1s, const float* __restrict__ W2s,
                        bf16_t* __restrict__ wshuf) {
    int t = blockIdx.x * blockDim.x + threadIdx.x;
    if (t >= 6 * 16384) return;
    int g  = t >> 14;
    int r  = t & 16383;
    int j  = r & 7;
    int L  = (r >> 3) & 63;
    int nt = (r >> 9) & 7;
    int ks = r >> 12;
    int l  = g >> 1;
    const float* src = (g & 1) ? (W2s + l * 16384) : (W1s + l * 16384);
    int k = ks * 32 + (L >> 4) * 8 + j;
    int n = nt * 16 + (L & 15);
    wshuf[t] = (bf16_t)src[k * DD + n];
}

__global__ void k_aff_init(float* __restrict__ ss) {
    int f = threadIdx.x;
    if (f < DD) { ss[f] = 1.0f; ss[DD + f] = 0.0f; }
}

__global__ void k_aff_update(const float* __restrict__ stats, const float* __restrict__ gamma,
                             const float* __restrict__ beta, float* __restrict__ scale,
                             float* __restrict__ shift) {
    int f = threadIdx.x;
    if (f < DD) {
        float mu  = stats[f] * (1.0f / N_NODES);
        float var = stats[DD + f] * (1.0f / N_NODES) - mu * mu;
        float inv = rsqrtf(var + BN_EPS);
        float sc  = gamma[f] * inv;
        scale[f] = sc;
        shift[f] = beta[f] - mu * sc;
    }
}

__global__ void k_gbounds(const int* __restrict__ batch, int* __restrict__ gstart) {
    int i = blockIdx.x * blockDim.x + threadIdx.x;
    if (i >= N_NODES) return;
    int b = batch[i];
    int bp = (i == 0) ? -1 : batch[i - 1];
    for (int g = bp + 1; g <= b; ++g) gstart[g] = i;
    if (i == N_NODES - 1)
        for (int g = b + 1; g <= N_GRAPHS; ++g) gstart[g] = N_NODES;
}

// ---------------- fused GIN layer (persistent, chunked gather) ----------------
// grid = 768 (3 blocks/CU, LDS-limited). Each block loops tiles of 64 nodes.
// Gather: per src-chunk flat edge loop, half-wave per edge, LDS fp32 atomics
// (accum stride 130 -> ds_add bank-conflict-free). All blocks sweep chunks in
// the same order so the live gather working set stays ~1-2 MB (L2-resident).
__global__ __launch_bounds__(256, 3) void k_layer(
    const bf16_t* __restrict__ xb, bf16_t* __restrict__ yb,
    const int* __restrict__ boff, const u32* __restrict__ csr2,
    const int* __restrict__ deg,
    const float* __restrict__ scale, const float* __restrict__ shift,
    const bf16_t* __restrict__ w1s, const bf16_t* __restrict__ w2s,
    const float* __restrict__ b1, const float* __restrict__ b2,
    float* __restrict__ stats)
{
    __shared__ float sAcc[64 * 130];              // 33.28 KB
    __shared__ __align__(16) bf16_t tile[64 * 136]; // 17.41 KB

    const int tid  = threadIdx.x;
    const int w    = tid >> 6;
    const int lane = tid & 63;
    const int h    = lane >> 5;
    const int li   = lane & 31;
    const int halfId = (w << 1) | h;   // 0..7
    const u16* xu = (const u16*)xb;
    const uint2* xb2 = (const uint2*)xb;

    for (int tileI = blockIdx.x; tileI < NTILES; tileI += GRID_LAYER) {
        const int base = tileI * 64;

        // ---- Phase 0: zero accumulators ----
        for (int i = tid; i < 64 * 130; i += 256) sAcc[i] = 0.f;
        __syncthreads();

        // ---- Phase 1: chunked flat edge gather ----
        for (int c = 0; c < NCHUNK; ++c) {
            int segB = boff[tileI * NCHUNK + c];
            int segE = boff[tileI * NCHUNK + c + 1];
            int len  = segE - segB;
            int per  = (len + 7) >> 3;
            int e    = segB + halfId * per;
            int eE   = e + per; if (eE > segE) eE = segE;

            for (; e + 4 <= eE; e += 4) {
                u32 v0 = csr2[e], v1 = csr2[e + 1], v2 = csr2[e + 2], v3 = csr2[e + 3];
                const u16* g0 = xu + ((size_t)(v0 & 0x1FFFF) << 7) + li;
                const u16* g1 = xu + ((size_t)(v1 & 0x1FFFF) << 7) + li;
                const u16* g2 = xu + ((size_t)(v2 & 0x1FFFF) << 7) + li;
                const u16* g3 = xu + ((size_t)(v3 & 0x1FFFF) << 7) + li;
                u32 a00 = g0[0], a01 = g0[32], a02 = g0[64], a03 = g0[96];
                u32 a10 = g1[0], a11 = g1[32], a12 = g1[64], a13 = g1[96];
                u32 a20 = g2[0], a21 = g2[32], a22 = g2[64], a23 = g2[96];
                u32 a30 = g3[0], a31 = g3[32], a32 = g3[64], a33 = g3[96];
                float* p0 = sAcc + (v0 >> 17) * 130 + li;
                float* p1 = sAcc + (v1 >> 17) * 130 + li;
                float* p2 = sAcc + (v2 >> 17) * 130 + li;
                float* p3 = sAcc + (v3 >> 17) * 130 + li;
                atomicAdd(p0 +  0, bfbits2f(a00)); atomicAdd(p0 + 32, bfbits2f(a01));
                atomicAdd(p0 + 64, bfbits2f(a02)); atomicAdd(p0 + 96, bfbits2f(a03));
                atomicAdd(p1 +  0, bfbits2f(a10)); atomicAdd(p1 + 32, bfbits2f(a11));
                atomicAdd(p1 + 64, bfbits2f(a12)); atomicAdd(p1 + 96, bfbits2f(a13));
                atomicAdd(p2 +  0, bfbits2f(a20)); atomicAdd(p2 + 32, bfbits2f(a21));
                atomicAdd(p2 + 64, bfbits2f(a22)); atomicAdd(p2 + 96, bfbits2f(a23));
                atomicAdd(p3 +  0, bfbits2f(a30)); atomicAdd(p3 + 32, bfbits2f(a31));
                atomicAdd(p3 + 64, bfbits2f(a32)); atomicAdd(p3 + 96, bfbits2f(a33));
            }
            for (; e < eE; ++e) {
                u32 v = csr2[e];
                const u16* g = xu + ((size_t)(v & 0x1FFFF) << 7) + li;
                u32 a0 = g[0], a1 = g[32], a2 = g[64], a3 = g[96];
                float* p = sAcc + (v >> 17) * 130 + li;
                atomicAdd(p +  0, bfbits2f(a0)); atomicAdd(p + 32, bfbits2f(a1));
                atomicAdd(p + 64, bfbits2f(a2)); atomicAdd(p + 96, bfbits2f(a3));
            }
        }
        __syncthreads();

        // ---- Phase 2: self + BN affine + convert -> tile ----
        // thread t: row = lane, feature group = w (features w*32 .. w*32+31)
        {
            int node = base + lane;
            if (node < N_NODES) {
                float cnt = (float)(deg[node] + 1);
                const uint2* xr = xb2 + (size_t)node * 32 + w * 8;
#pragma unroll
                for (int j = 0; j < 8; ++j) {
                    uint2 sl = xr[j];
                    int f = w * 32 + j * 4;
                    float v0 = (bfbits2f(sl.x & 0xffffu) + sAcc[lane * 130 + f + 0]) * scale[f + 0] + cnt * shift[f + 0];
                    float v1 = (bfbits2f(sl.x >> 16)     + sAcc[lane * 130 + f + 1]) * scale[f + 1] + cnt * shift[f + 1];
                    float v2 = (bfbits2f(sl.y & 0xffffu) + sAcc[lane * 130 + f + 2]) * scale[f + 2] + cnt * shift[f + 2];
                    float v3 = (bfbits2f(sl.y >> 16)     + sAcc[lane * 130 + f + 3]) * scale[f + 3] + cnt * shift[f + 3];
                    bf16x4 pk;
                    pk.x = (bf16_t)v0; pk.y = (bf16_t)v1; pk.z = (bf16_t)v2; pk.w = (bf16_t)v3;
                    *(bf16x4*)(&tile[lane * 136 + f]) = pk;
                }
            } else {
                bf16x4 z; z.x = (bf16_t)0.f; z.y = (bf16_t)0.f; z.z = (bf16_t)0.f; z.w = (bf16_t)0.f;
#pragma unroll
                for (int j = 0; j < 8; ++j)
                    *(bf16x4*)(&tile[lane * 136 + w * 32 + j * 4]) = z;
            }
        }
        __syncthreads();

        // ---- Phase 3: GEMM1 + bias + relu -> tile (reused) ----
        const int q = lane >> 4;
        const int c16 = lane & 15;
        const int arow = (w << 4) + c16;

        bf16x8 afr[4];
#pragma unroll
        for (int ks = 0; ks < 4; ++ks)
            afr[ks] = *(const bf16x8*)(&tile[arow * 136 + ks * 32 + q * 8]);
        __syncthreads();

        f32x4 acc[8];
#pragma unroll
        for (int nt = 0; nt < 8; ++nt) acc[nt] = (f32x4){0.f, 0.f, 0.f, 0.f};
#pragma unroll
        for (int ks = 0; ks < 4; ++ks) {
#pragma unroll
            for (int nt = 0; nt < 8; ++nt) {
                bf16x8 bfr = *(const bf16x8*)(w1s + (((ks << 3) + nt) * 64 + lane) * 8);
                acc[nt] = __builtin_amdgcn_mfma_f32_16x16x32_bf16(afr[ks], bfr, acc[nt], 0, 0, 0);
            }
        }
#pragma unroll
        for (int nt = 0; nt < 8; ++nt) {
            float bias = b1[(nt << 4) + c16];
#pragma unroll
            for (int i = 0; i < 4; ++i) {
                float v = fmaxf(acc[nt][i] + bias, 0.f);
                int row = (w << 4) + (q << 2) + i;
                tile[row * 136 + (nt << 4) + c16] = (bf16_t)v;
            }
        }
        __syncthreads();

        // ---- Phase 4: GEMM2 + bias + relu + BN stats + store ----
        bf16x8 afr2[4];
#pragma unroll
        for (int ks = 0; ks < 4; ++ks)
            afr2[ks] = *(const bf16x8*)(&tile[arow * 136 + ks * 32 + q * 8]);

#pragma unroll
        for (int nt = 0; nt < 8; ++nt) acc[nt] = (f32x4){0.f, 0.f, 0.f, 0.f};
#pragma unroll
        for (int ks = 0; ks < 4; ++ks) {
#pragma unroll
            for (int nt = 0; nt < 8; ++nt) {
                bf16x8 bfr = *(const bf16x8*)(w2s + (((ks << 3) + nt) * 64 + lane) * 8);
                acc[nt] = __builtin_amdgcn_mfma_f32_16x16x32_bf16(afr2[ks], bfr, acc[nt], 0, 0, 0);
            }
        }
#pragma unroll
        for (int nt = 0; nt < 8; ++nt) {
            float bias = b2[(nt << 4) + c16];
            float s1 = 0.f, s2 = 0.f;
#pragma unroll
            for (int i = 0; i < 4; ++i) {
                float v = fmaxf(acc[nt][i] + bias, 0.f);
                int row = (w << 4) + (q << 2) + i;
                int node = base + row;
                if (node < N_NODES) {
                    s1 += v;
                    s2 += v * v;
                    yb[(size_t)node * DD + (nt << 4) + c16] = (bf16_t)v;
                }
            }
            s1 += __shfl_down(s1, 32); s2 += __shfl_down(s2, 32);
            s1 += __shfl_down(s1, 16); s2 += __shfl_down(s2, 16);
            if (lane < 16) {
                atomicAdd(&stats[(nt << 4) + lane], s1);
                atomicAdd(&stats[DD + (nt << 4) + lane], s2);
            }
        }
        __syncthreads(); // tile/sAcc reused next iteration
    }
}

// ---------------- pooling + head ----------------

__global__ __launch_bounds__(128) void k_pool2(
    const bf16_t* __restrict__ yb, const int* __restrict__ gstart,
    const float* __restrict__ scale, const float* __restrict__ shift,
    float* __restrict__ pooled)
{
    int g = blockIdx.x;
    int t = threadIdx.x;
    int s = gstart[g], e = gstart[g + 1];
    float acc = 0.f;
    for (int n = s; n < e; ++n)
        acc += (float)yb[(size_t)n * DD + t];
    float cnt = (float)(e - s);
    float v = acc * scale[t] + cnt * shift[t];
    pooled[g * DD + t] = v / fmaxf(cnt, 1.0f);
}

__global__ void k_head(const float* __restrict__ pooled,
                       const float* __restrict__ lin1w, const float* __restrict__ lin1b,
                       const float* __restrict__ lin2w, const float* __restrict__ lin2b,
                       float* __restrict__ out) {
    __shared__ float p[DD];
    __shared__ float h[DD];
    int g = blockIdx.x;
    int t = threadIdx.x;
    p[t] = pooled[g * DD + t];
    __syncthreads();
    float a = lin1b[t];
    for (int k = 0; k < DD; ++k) a += p[k] * lin1w[k * DD + t];
    h[t] = fmaxf(a, 0.f);
    __syncthreads();
    if (t < 10) {
        float o = lin2b[t];
        for (int k = 0; k < DD; ++k) o += h[k] * lin2w[k * 10 + t];
        out[g * 10 + t] = o;
    }
}

// ---------------- launch ----------------

extern "C" void kernel_launch(void* const* d_in, const int* in_sizes, int n_in,
                              void* d_out, int out_size, void* d_ws, size_t ws_size,
                              hipStream_t stream) {
    const float* x      = (const float*)d_in[0];
    const int*   ei     = (const int*)d_in[1];
    const int*   batch  = (const int*)d_in[2];
    const float* W1s    = (const float*)d_in[3];
    const float* b1s    = (const float*)d_in[4];
    const float* W2s    = (const float*)d_in[5];
    const float* b2s    = (const float*)d_in[6];
    const float* gammas = (const float*)d_in[7];
    const float* betas  = (const float*)d_in[8];
    const float* lin1w  = (const float*)d_in[9];
    const float* lin1b  = (const float*)d_in[10];
    const float* lin2w  = (const float*)d_in[11];
    const float* lin2b  = (const float*)d_in[12];
    float* out = (float*)d_out;

    char* p = (char*)d_ws;
    size_t off = 0;
    auto alloc = [&](size_t bytes) -> char* {
        char* r = p + off;
        off += (bytes + 255) & ~(size_t)255;
        return r;
    };
    int*    deg    = (int*)alloc(N_NODES * 4);
    int*    bcnt   = (int*)alloc(NBUCKETS * 4);
    float*  stats  = (float*)alloc(3 * 256 * 4);
    size_t zero_bytes = off;
    int*    boff   = (int*)alloc((NBUCKETS + 1) * 4);
    int*    bcur   = (int*)alloc(NBUCKETS * 4);
    u32*    csr2   = (u32*)alloc((N_EDGES + 8) * 4);
    bf16_t* xb     = (bf16_t*)alloc((size_t)N_NODES * DD * 2);
    bf16_t* yb     = (bf16_t*)alloc((size_t)N_NODES * DD * 2);
    bf16_t* wshuf  = (bf16_t*)alloc(6 * 16384 * 2);
    float*  ss     = (float*)alloc(4 * 256 * 4);
    int*    gstart = (int*)alloc((N_GRAPHS + 1) * 4);
    float*  pooled = (float*)alloc(N_GRAPHS * DD * 4);
    if (off > ws_size) return;

    const int* srcA = ei;
    const int* dstA = ei + N_EDGES;

    k_zero<<<256, 256, 0, stream>>>((float4*)d_ws, (int)(zero_bytes / 16));
    k_hist2<<<1024, 256, 0, stream>>>(srcA, dstA, deg, bcnt);
    k_scan2<<<1, 1024, 0, stream>>>(bcnt, boff, bcur);
    k_fill2<<<1024, 256, 0, stream>>>(srcA, dstA, bcur, csr2);
    k_cvt<<<1024, 256, 0, stream>>>(x, xb);
    k_shufw<<<(6 * 16384 + 255) / 256, 256, 0, stream>>>(W1s, W2s, wshuf);
    k_aff_init<<<1, 128, 0, stream>>>(ss);
    k_gbounds<<<(N_NODES + 255) / 256, 256, 0, stream>>>(batch, gstart);

    bf16_t* bufs[2] = { xb, yb };
    for (int l = 0; l < 3; ++l) {
        k_layer<<<GRID_LAYER, 256, 0, stream>>>(
            bufs[l & 1], bufs[(l + 1) & 1], boff, csr2, deg,
            ss + l * 256, ss + l * 256 + 128,
            wshuf + (2 * l) * 16384, wshuf + (2 * l + 1) * 16384,
            b1s + l * DD, b2s + l * DD, stats + l * 256);
        k_aff_update<<<1, 128, 0, stream>>>(stats + l * 256, gammas + l * DD, betas + l * DD,
                                            ss + (l + 1) * 256, ss + (l + 1) * 256 + 128);
    }
    k_pool2<<<N_GRAPHS, 128, 0, stream>>>(bufs[1], gstart, ss + 3 * 256, ss + 3 * 256 + 128, pooled);
    k_head<<<N_GRAPHS, 128, 0, stream>>>(pooled, lin1w, lin1b, lin2w, lin2b, out);
}

// Round 5
// 1337.898 us; speedup vs baseline: 3.1885x; 3.1885x over previous
//
#include <hip/hip_runtime.h>
#include <hip/hip_bf16.h>

#define N_NODES 100000
#define N_EDGES 1600000
#define DD 128
#define N_GRAPHS 512
#define BN_EPS 1e-5f
#define NTILES 1563            // ceil(100000/64)

typedef unsigned int u32;
typedef __bf16 bf16_t;
typedef __bf16 bf16x4 __attribute__((ext_vector_type(4)));
typedef __bf16 bf16x8 __attribute__((ext_vector_type(8)));
typedef float f32x4 __attribute__((ext_vector_type(4)));

__device__ __forceinline__ float bflo2f(u32 u) {
    union { u32 i; float f; } x; x.i = u << 16; return x.f;
}
__device__ __forceinline__ float bfhi2f(u32 u) {
    union { u32 i; float f; } x; x.i = u & 0xffff0000u; return x.f;
}

// ---------------- utility kernels ----------------

__global__ void k_zero(float4* p, int n) {
    float4 z = make_float4(0.f, 0.f, 0.f, 0.f);
    for (int i = blockIdx.x * blockDim.x + threadIdx.x; i < n; i += gridDim.x * blockDim.x)
        p[i] = z;
}

__global__ void k_hist(const int* __restrict__ dst, int* __restrict__ deg) {
    for (int e = blockIdx.x * blockDim.x + threadIdx.x; e < N_EDGES; e += gridDim.x * blockDim.x)
        atomicAdd(&deg[dst[e]], 1);
}

// single block: exclusive scan of padded degrees ((deg+7)&~7) -> poffs, cursor
__global__ void k_scan(const int* __restrict__ deg, int* __restrict__ poffs, int* __restrict__ cursor) {
    __shared__ int ps[1024];
    int t = threadIdx.x;
    int s = 0;
    if (t < 1000) {
        const int4* d4 = (const int4*)(deg + t * 100);
        for (int i = 0; i < 25; ++i) {
            int4 v = d4[i];
            s += ((v.x + 7) & ~7) + ((v.y + 7) & ~7) + ((v.z + 7) & ~7) + ((v.w + 7) & ~7);
        }
    }
    ps[t] = s;
    __syncthreads();
    for (int d2 = 1; d2 < 1024; d2 <<= 1) {
        int v = (t >= d2) ? ps[t - d2] : 0;
        __syncthreads();
        ps[t] += v;
        __syncthreads();
    }
    int run = ps[t] - s;
    if (t < 1000) {
        for (int i = 0; i < 100; ++i) {
            int idx = t * 100 + i;
            poffs[idx] = run; cursor[idx] = run;
            run += (deg[idx] + 7) & ~7;
        }
    }
    if (t == 1023) poffs[N_NODES] = ps[1023];
}

__global__ void k_fill(const int* __restrict__ src, const int* __restrict__ dst,
                       int* __restrict__ cursor, int* __restrict__ csr) {
    for (int e = blockIdx.x * blockDim.x + threadIdx.x; e < N_EDGES; e += gridDim.x * blockDim.x) {
        int pos = atomicAdd(&cursor[dst[e]], 1);
        csr[pos] = src[e];
    }
}

// fill pad slots [poffs[n]+deg[n], poffs[n+1]) with the zero-row index N_NODES
__global__ void k_pad(const int* __restrict__ deg, const int* __restrict__ poffs,
                      int* __restrict__ csr) {
    int t = blockIdx.x * blockDim.x + threadIdx.x;
    if (t >= N_NODES * 8) return;
    int n = t >> 3, j = t & 7;
    int s = poffs[n] + deg[n];
    if (s + j < poffs[n + 1]) csr[s + j] = N_NODES;
}

__global__ void k_cvt(const float* __restrict__ x, bf16_t* __restrict__ xb) {
    const int n4 = N_NODES * DD / 4;
    const float4* x4 = (const float4*)x;
    bf16x4* o4 = (bf16x4*)xb;
    for (int i = blockIdx.x * blockDim.x + threadIdx.x; i < n4; i += gridDim.x * blockDim.x) {
        float4 v = x4[i];
        bf16x4 o;
        o.x = (bf16_t)v.x; o.y = (bf16_t)v.y; o.z = (bf16_t)v.z; o.w = (bf16_t)v.w;
        o4[i] = o;
    }
}

// zero row N_NODES of both feature buffers (gather target for pad edges)
__global__ void k_zrow(bf16_t* __restrict__ xb, bf16_t* __restrict__ yb) {
    int t = threadIdx.x;
    xb[(size_t)N_NODES * DD + t] = (bf16_t)0.f;
    yb[(size_t)N_NODES * DD + t] = (bf16_t)0.f;
}

// Pre-shuffle the 6 weight matrices into exact MFMA B-fragment order (bf16).
__global__ void k_shufw(const float* __restrict__ W1s, const float* __restrict__ W2s,
                        bf16_t* __restrict__ wshuf) {
    int t = blockIdx.x * blockDim.x + threadIdx.x;
    if (t >= 6 * 16384) return;
    int g  = t >> 14;
    int r  = t & 16383;
    int j  = r & 7;
    int L  = (r >> 3) & 63;
    int nt = (r >> 9) & 7;
    int ks = r >> 12;
    int l  = g >> 1;
    const float* src = (g & 1) ? (W2s + l * 16384) : (W1s + l * 16384);
    int k = ks * 32 + (L >> 4) * 8 + j;
    int n = nt * 16 + (L & 15);
    wshuf[t] = (bf16_t)src[k * DD + n];
}

__global__ void k_aff_init(float* __restrict__ ss) {
    int f = threadIdx.x;
    if (f < DD) { ss[f] = 1.0f; ss[DD + f] = 0.0f; }
}

__global__ void k_aff_update(const float* __restrict__ stats, const float* __restrict__ gamma,
                             const float* __restrict__ beta, float* __restrict__ scale,
                             float* __restrict__ shift) {
    int f = threadIdx.x;
    if (f < DD) {
        float mu  = stats[f] * (1.0f / N_NODES);
        float var = stats[DD + f] * (1.0f / N_NODES) - mu * mu;
        float inv = rsqrtf(var + BN_EPS);
        float sc  = gamma[f] * inv;
        scale[f] = sc;
        shift[f] = beta[f] - mu * sc;
    }
}

__global__ void k_gbounds(const int* __restrict__ batch, int* __restrict__ gstart) {
    int i = blockIdx.x * blockDim.x + threadIdx.x;
    if (i >= N_NODES) return;
    int b = batch[i];
    int bp = (i == 0) ? -1 : batch[i - 1];
    for (int g = bp + 1; g <= b; ++g) gstart[g] = i;
    if (i == N_NODES - 1)
        for (int g = b + 1; g <= N_GRAPHS; ++g) gstart[g] = N_NODES;
}

// ---------------- fused GIN layer ----------------
// block = 256 (4 waves), 64 nodes. Gather: wave per node, lane = (quarter sub,
// uint4 fl): one dwordx4 gather instr covers 4 edges (1 KB); 8 edges/iter via
// int2 index load. Edge lists padded to x8 with zero-row -> no tails/divergence.
__global__ __launch_bounds__(256, 8) void k_layer(
    const bf16_t* __restrict__ xb, bf16_t* __restrict__ yb,
    const int* __restrict__ poffs, const int* __restrict__ csr,
    const int* __restrict__ deg,
    const float* __restrict__ scale, const float* __restrict__ shift,
    const bf16_t* __restrict__ w1s, const bf16_t* __restrict__ w2s,
    const float* __restrict__ b1, const float* __restrict__ b2,
    float* __restrict__ stats)
{
    __shared__ __align__(16) bf16_t tile[64 * 136];

    const int tid  = threadIdx.x;
    const int w    = tid >> 6;
    const int lane = tid & 63;
    const int base = blockIdx.x * 64;
    const int sub  = lane >> 4;
    const int fl   = lane & 15;

    const uint4* x4 = (const uint4*)xb;   // 16 uint4 per row

    // hoisted BN affine for this lane's 8 features
    float sc[8], sh[8];
    {
        const float4* s4 = (const float4*)(scale + fl * 8);
        const float4* h4 = (const float4*)(shift + fl * 8);
        float4 A = s4[0], B = s4[1], C = h4[0], E = h4[1];
        sc[0]=A.x; sc[1]=A.y; sc[2]=A.z; sc[3]=A.w; sc[4]=B.x; sc[5]=B.y; sc[6]=B.z; sc[7]=B.w;
        sh[0]=C.x; sh[1]=C.y; sh[2]=C.z; sh[3]=C.w; sh[4]=E.x; sh[5]=E.y; sh[6]=E.z; sh[7]=E.w;
    }

    // ---- Phase 1: gather + self + BN affine -> tile ----
    for (int r = 0; r < 16; ++r) {
        int row = (w << 4) + r;
        int node = base + row;
        if (node < N_NODES) {
            float a0=0.f,a1=0.f,a2=0.f,a3=0.f,a4=0.f,a5=0.f,a6=0.f,a7=0.f;
            int e  = poffs[node];
            int eE = poffs[node + 1];
            for (; e < eE; e += 8) {
                int2 ij = *(const int2*)(csr + e + sub * 2);
                uint4 r0 = x4[(size_t)ij.x * 16 + fl];
                uint4 r1 = x4[(size_t)ij.y * 16 + fl];
                a0 += bflo2f(r0.x); a1 += bfhi2f(r0.x);
                a2 += bflo2f(r0.y); a3 += bfhi2f(r0.y);
                a4 += bflo2f(r0.z); a5 += bfhi2f(r0.z);
                a6 += bflo2f(r0.w); a7 += bfhi2f(r0.w);
                a0 += bflo2f(r1.x); a1 += bfhi2f(r1.x);
                a2 += bflo2f(r1.y); a3 += bfhi2f(r1.y);
                a4 += bflo2f(r1.z); a5 += bfhi2f(r1.z);
                a6 += bflo2f(r1.w); a7 += bfhi2f(r1.w);
            }
            // reduce across the 4 quarters (lanes fl, fl+16, fl+32, fl+48)
            a0 += __shfl_xor(a0, 32); a1 += __shfl_xor(a1, 32);
            a2 += __shfl_xor(a2, 32); a3 += __shfl_xor(a3, 32);
            a4 += __shfl_xor(a4, 32); a5 += __shfl_xor(a5, 32);
            a6 += __shfl_xor(a6, 32); a7 += __shfl_xor(a7, 32);
            a0 += __shfl_xor(a0, 16); a1 += __shfl_xor(a1, 16);
            a2 += __shfl_xor(a2, 16); a3 += __shfl_xor(a3, 16);
            a4 += __shfl_xor(a4, 16); a5 += __shfl_xor(a5, 16);
            a6 += __shfl_xor(a6, 16); a7 += __shfl_xor(a7, 16);

            uint4 s = x4[(size_t)node * 16 + fl];
            float cnt = (float)(deg[node] + 1);
            float v0 = (a0 + bflo2f(s.x)) * sc[0] + cnt * sh[0];
            float v1 = (a1 + bfhi2f(s.x)) * sc[1] + cnt * sh[1];
            float v2 = (a2 + bflo2f(s.y)) * sc[2] + cnt * sh[2];
            float v3 = (a3 + bfhi2f(s.y)) * sc[3] + cnt * sh[3];
            float v4 = (a4 + bflo2f(s.z)) * sc[4] + cnt * sh[4];
            float v5 = (a5 + bfhi2f(s.z)) * sc[5] + cnt * sh[5];
            float v6 = (a6 + bflo2f(s.w)) * sc[6] + cnt * sh[6];
            float v7 = (a7 + bfhi2f(s.w)) * sc[7] + cnt * sh[7];
            if (lane < 16) {
                bf16x8 pk;
                pk[0]=(bf16_t)v0; pk[1]=(bf16_t)v1; pk[2]=(bf16_t)v2; pk[3]=(bf16_t)v3;
                pk[4]=(bf16_t)v4; pk[5]=(bf16_t)v5; pk[6]=(bf16_t)v6; pk[7]=(bf16_t)v7;
                *(bf16x8*)(&tile[row * 136 + fl * 8]) = pk;
            }
        } else if (lane < 16) {
            bf16x8 z;
#pragma unroll
            for (int j = 0; j < 8; ++j) z[j] = (bf16_t)0.f;
            *(bf16x8*)(&tile[row * 136 + fl * 8]) = z;
        }
    }
    __syncthreads();

    // ---- Phase 2: GEMM1 + bias + relu -> tile (reused) ----
    const int q = lane >> 4;
    const int c16 = lane & 15;
    const int arow = (w << 4) + c16;

    bf16x8 afr[4];
#pragma unroll
    for (int ks = 0; ks < 4; ++ks)
        afr[ks] = *(const bf16x8*)(&tile[arow * 136 + ks * 32 + q * 8]);
    __syncthreads();

    f32x4 acc[8];
#pragma unroll
    for (int nt = 0; nt < 8; ++nt) acc[nt] = (f32x4){0.f, 0.f, 0.f, 0.f};
#pragma unroll
    for (int ks = 0; ks < 4; ++ks) {
#pragma unroll
        for (int nt = 0; nt < 8; ++nt) {
            bf16x8 bfr = *(const bf16x8*)(w1s + (((ks << 3) + nt) * 64 + lane) * 8);
            acc[nt] = __builtin_amdgcn_mfma_f32_16x16x32_bf16(afr[ks], bfr, acc[nt], 0, 0, 0);
        }
    }
#pragma unroll
    for (int nt = 0; nt < 8; ++nt) {
        float bias = b1[(nt << 4) + c16];
#pragma unroll
        for (int i = 0; i < 4; ++i) {
            float v = fmaxf(acc[nt][i] + bias, 0.f);
            int row = (w << 4) + (q << 2) + i;
            tile[row * 136 + (nt << 4) + c16] = (bf16_t)v;
        }
    }
    __syncthreads();

    // ---- Phase 3: GEMM2 + bias + relu + BN stats + store ----
    bf16x8 afr2[4];
#pragma unroll
    for (int ks = 0; ks < 4; ++ks)
        afr2[ks] = *(const bf16x8*)(&tile[arow * 136 + ks * 32 + q * 8]);

#pragma unroll
    for (int nt = 0; nt < 8; ++nt) acc[nt] = (f32x4){0.f, 0.f, 0.f, 0.f};
#pragma unroll
    for (int ks = 0; ks < 4; ++ks) {
#pragma unroll
        for (int nt = 0; nt < 8; ++nt) {
            bf16x8 bfr = *(const bf16x8*)(w2s + (((ks << 3) + nt) * 64 + lane) * 8);
            acc[nt] = __builtin_amdgcn_mfma_f32_16x16x32_bf16(afr2[ks], bfr, acc[nt], 0, 0, 0);
        }
    }
#pragma unroll
    for (int nt = 0; nt < 8; ++nt) {
        float bias = b2[(nt << 4) + c16];
        float s1 = 0.f, s2 = 0.f;
#pragma unroll
        for (int i = 0; i < 4; ++i) {
            float v = fmaxf(acc[nt][i] + bias, 0.f);
            int row = (w << 4) + (q << 2) + i;
            int node = base + row;
            if (node < N_NODES) {
                s1 += v;
                s2 += v * v;
                yb[(size_t)node * DD + (nt << 4) + c16] = (bf16_t)v;
            }
        }
        s1 += __shfl_down(s1, 32); s2 += __shfl_down(s2, 32);
        s1 += __shfl_down(s1, 16); s2 += __shfl_down(s2, 16);
        if (lane < 16) {
            atomicAdd(&stats[(nt << 4) + lane], s1);
            atomicAdd(&stats[DD + (nt << 4) + lane], s2);
        }
    }
}

// ---------------- pooling + head ----------------

__global__ __launch_bounds__(128) void k_pool2(
    const bf16_t* __restrict__ yb, const int* __restrict__ gstart,
    const float* __restrict__ scale, const float* __restrict__ shift,
    float* __restrict__ pooled)
{
    int g = blockIdx.x;
    int t = threadIdx.x;
    int s = gstart[g], e = gstart[g + 1];
    float acc = 0.f;
    for (int n = s; n < e; ++n)
        acc += (float)yb[(size_t)n * DD + t];
    float cnt = (float)(e - s);
    float v = acc * scale[t] + cnt * shift[t];
    pooled[g * DD + t] = v / fmaxf(cnt, 1.0f);
}

__global__ void k_head(const float* __restrict__ pooled,
                       const float* __restrict__ lin1w, const float* __restrict__ lin1b,
                       const float* __restrict__ lin2w, const float* __restrict__ lin2b,
                       float* __restrict__ out) {
    __shared__ float p[DD];
    __shared__ float h[DD];
    int g = blockIdx.x;
    int t = threadIdx.x;
    p[t] = pooled[g * DD + t];
    __syncthreads();
    float a = lin1b[t];
    for (int k = 0; k < DD; ++k) a += p[k] * lin1w[k * DD + t];
    h[t] = fmaxf(a, 0.f);
    __syncthreads();
    if (t < 10) {
        float o = lin2b[t];
        for (int k = 0; k < DD; ++k) o += h[k] * lin2w[k * 10 + t];
        out[g * 10 + t] = o;
    }
}

// ---------------- launch ----------------

extern "C" void kernel_launch(void* const* d_in, const int* in_sizes, int n_in,
                              void* d_out, int out_size, void* d_ws, size_t ws_size,
                              hipStream_t stream) {
    const float* x      = (const float*)d_in[0];
    const int*   ei     = (const int*)d_in[1];
    const int*   batch  = (const int*)d_in[2];
    const float* W1s    = (const float*)d_in[3];
    const float* b1s    = (const float*)d_in[4];
    const float* W2s    = (const float*)d_in[5];
    const float* b2s    = (const float*)d_in[6];
    const float* gammas = (const float*)d_in[7];
    const float* betas  = (const float*)d_in[8];
    const float* lin1w  = (const float*)d_in[9];
    const float* lin1b  = (const float*)d_in[10];
    const float* lin2w  = (const float*)d_in[11];
    const float* lin2b  = (const float*)d_in[12];
    float* out = (float*)d_out;

    char* p = (char*)d_ws;
    size_t off = 0;
    auto alloc = [&](size_t bytes) -> char* {
        char* r = p + off;
        off += (bytes + 255) & ~(size_t)255;
        return r;
    };
    int*    deg    = (int*)alloc(N_NODES * 4);
    float*  stats  = (float*)alloc(3 * 256 * 4);
    size_t zero_bytes = off;
    int*    poffs  = (int*)alloc((N_NODES + 1) * 4);
    int*    cursor = (int*)alloc(N_NODES * 4);
    int*    csr    = (int*)alloc((N_EDGES + 8 * N_NODES + 16) * 4); // padded capacity
    bf16_t* xb     = (bf16_t*)alloc(((size_t)N_NODES + 1) * DD * 2);
    bf16_t* yb     = (bf16_t*)alloc(((size_t)N_NODES + 1) * DD * 2);
    bf16_t* wshuf  = (bf16_t*)alloc(6 * 16384 * 2);
    float*  ss     = (float*)alloc(4 * 256 * 4);
    int*    gstart = (int*)alloc((N_GRAPHS + 1) * 4);
    float*  pooled = (float*)alloc(N_GRAPHS * DD * 4);
    if (off > ws_size) return;

    const int* srcA = ei;
    const int* dstA = ei + N_EDGES;

    k_zero<<<256, 256, 0, stream>>>((float4*)d_ws, (int)(zero_bytes / 16));
    k_hist<<<1024, 256, 0, stream>>>(dstA, deg);
    k_scan<<<1, 1024, 0, stream>>>(deg, poffs, cursor);
    k_fill<<<1024, 256, 0, stream>>>(srcA, dstA, cursor, csr);
    k_pad<<<(N_NODES * 8 + 255) / 256, 256, 0, stream>>>(deg, poffs, csr);
    k_cvt<<<1024, 256, 0, stream>>>(x, xb);
    k_zrow<<<1, 128, 0, stream>>>(xb, yb);
    k_shufw<<<(6 * 16384 + 255) / 256, 256, 0, stream>>>(W1s, W2s, wshuf);
    k_aff_init<<<1, 128, 0, stream>>>(ss);
    k_gbounds<<<(N_NODES + 255) / 256, 256, 0, stream>>>(batch, gstart);

    bf16_t* bufs[2] = { xb, yb };
    for (int l = 0; l < 3; ++l) {
        k_layer<<<NTILES, 256, 0, stream>>>(
            bufs[l & 1], bufs[(l + 1) & 1], poffs, csr, deg,
            ss + l * 256, ss + l * 256 + 128,
            wshuf + (2 * l) * 16384, wshuf + (2 * l + 1) * 16384,
            b1s + l * DD, b2s + l * DD, stats + l * 256);
        k_aff_update<<<1, 128, 0, stream>>>(stats + l * 256, gammas + l * DD, betas + l * DD,
                                            ss + (l + 1) * 256, ss + (l + 1) * 256 + 128);
    }
    k_pool2<<<N_GRAPHS, 128, 0, stream>>>(bufs[1], gstart, ss + 3 * 256, ss + 3 * 256 + 128, pooled);
    k_head<<<N_GRAPHS, 128, 0, stream>>>(pooled, lin1w, lin1b, lin2w, lin2b, out);
}

// Round 8
// 1220.050 us; speedup vs baseline: 3.4965x; 1.0966x over previous
//
#include <hip/hip_runtime.h>
#include <hip/hip_bf16.h>

#define N_NODES 100000
#define N_EDGES 1600000
#define DD 128
#define N_GRAPHS 512
#define BN_EPS 1e-5f
#define NTILES 1563            // ceil(100000/64)

typedef unsigned int u32;
typedef unsigned char u8;
typedef __bf16 bf16_t;
typedef __bf16 bf16x4 __attribute__((ext_vector_type(4)));
typedef __bf16 bf16x8 __attribute__((ext_vector_type(8)));
typedef float f32x4 __attribute__((ext_vector_type(4)));

__device__ __forceinline__ float bflo2f(u32 u) {
    union { u32 i; float f; } x; x.i = u << 16; return x.f;
}
__device__ __forceinline__ float bfhi2f(u32 u) {
    union { u32 i; float f; } x; x.i = u & 0xffff0000u; return x.f;
}
// accumulate 8 bf16 features (uint4) into a[0..7]
__device__ __forceinline__ void accbf(float* a, uint4 r) {
    a[0] += bflo2f(r.x); a[1] += bfhi2f(r.x);
    a[2] += bflo2f(r.y); a[3] += bfhi2f(r.y);
    a[4] += bflo2f(r.z); a[5] += bfhi2f(r.z);
    a[6] += bflo2f(r.w); a[7] += bfhi2f(r.w);
}
// accumulate 8 uint8 features (uint2) scaled by s into a[0..7]
__device__ __forceinline__ void acc8u(float* a, uint2 q, float s) {
#pragma unroll
    for (int j = 0; j < 4; ++j)
        a[j] += s * (float)((q.x >> (8 * j)) & 0xffu);
#pragma unroll
    for (int j = 0; j < 4; ++j)
        a[4 + j] += s * (float)((q.y >> (8 * j)) & 0xffu);
}
__device__ __forceinline__ u32 pack4u(float v0, float v1, float v2, float v3, float inv) {
    u32 q0 = (u32)fminf(rintf(v0 * inv), 255.f);
    u32 q1 = (u32)fminf(rintf(v1 * inv), 255.f);
    u32 q2 = (u32)fminf(rintf(v2 * inv), 255.f);
    u32 q3 = (u32)fminf(rintf(v3 * inv), 255.f);
    return q0 | (q1 << 8) | (q2 << 16) | (q3 << 24);
}

// ---------------- utility kernels ----------------

__global__ void k_zero(float4* p, int n) {
    float4 z = make_float4(0.f, 0.f, 0.f, 0.f);
    for (int i = blockIdx.x * blockDim.x + threadIdx.x; i < n; i += gridDim.x * blockDim.x)
        p[i] = z;
}

__global__ void k_hist(const int* __restrict__ dst, int* __restrict__ deg) {
    for (int e = blockIdx.x * blockDim.x + threadIdx.x; e < N_EDGES; e += gridDim.x * blockDim.x)
        atomicAdd(&deg[dst[e]], 1);
}

// single block: exclusive scan of padded degrees ((deg+7)&~7) -> poffs, cursor
__global__ void k_scan(const int* __restrict__ deg, int* __restrict__ poffs, int* __restrict__ cursor) {
    __shared__ int ps[1024];
    int t = threadIdx.x;
    int s = 0;
    if (t < 1000) {
        const int4* d4 = (const int4*)(deg + t * 100);
        for (int i = 0; i < 25; ++i) {
            int4 v = d4[i];
            s += ((v.x + 7) & ~7) + ((v.y + 7) & ~7) + ((v.z + 7) & ~7) + ((v.w + 7) & ~7);
        }
    }
    ps[t] = s;
    __syncthreads();
    for (int d2 = 1; d2 < 1024; d2 <<= 1) {
        int v = (t >= d2) ? ps[t - d2] : 0;
        __syncthreads();
        ps[t] += v;
        __syncthreads();
    }
    int run = ps[t] - s;
    if (t < 1000) {
        for (int i = 0; i < 100; ++i) {
            int idx = t * 100 + i;
            poffs[idx] = run; cursor[idx] = run;
            run += (deg[idx] + 7) & ~7;
        }
    }
    if (t == 1023) poffs[N_NODES] = ps[1023];
}

__global__ void k_fill(const int* __restrict__ src, const int* __restrict__ dst,
                       int* __restrict__ cursor, int* __restrict__ csr) {
    for (int e = blockIdx.x * blockDim.x + threadIdx.x; e < N_EDGES; e += gridDim.x * blockDim.x) {
        int pos = atomicAdd(&cursor[dst[e]], 1);
        csr[pos] = src[e];
    }
}

// fill pad slots with the zero-row index N_NODES
__global__ void k_pad(const int* __restrict__ deg, const int* __restrict__ poffs,
                      int* __restrict__ csr) {
    int t = blockIdx.x * blockDim.x + threadIdx.x;
    if (t >= N_NODES * 8) return;
    int n = t >> 3, j = t & 7;
    int s = poffs[n] + deg[n];
    if (s + j < poffs[n + 1]) csr[s + j] = N_NODES;
}

__global__ void k_cvt(const float* __restrict__ x, bf16_t* __restrict__ xb) {
    const int n4 = N_NODES * DD / 4;
    const float4* x4 = (const float4*)x;
    bf16x4* o4 = (bf16x4*)xb;
    for (int i = blockIdx.x * blockDim.x + threadIdx.x; i < n4; i += gridDim.x * blockDim.x) {
        float4 v = x4[i];
        bf16x4 o;
        o.x = (bf16_t)v.x; o.y = (bf16_t)v.y; o.z = (bf16_t)v.z; o.w = (bf16_t)v.w;
        o4[i] = o;
    }
}

// zero pad row of the bf16 input buffer
__global__ void k_zrow(bf16_t* __restrict__ xb) {
    xb[(size_t)N_NODES * DD + threadIdx.x] = (bf16_t)0.f;
}

// zero pad row + scale of a u8 buffer
__global__ void k_zrow8(u8* __restrict__ a, float* __restrict__ sa) {
    a[(size_t)N_NODES * DD + threadIdx.x] = 0;
    if (threadIdx.x == 0) sa[N_NODES] = 0.f;
}

// Pre-shuffle the 6 weight matrices into exact MFMA B-fragment order (bf16).
__global__ void k_shufw(const float* __restrict__ W1s, const float* __restrict__ W2s,
                        bf16_t* __restrict__ wshuf) {
    int t = blockIdx.x * blockDim.x + threadIdx.x;
    if (t >= 6 * 16384) return;
    int g  = t >> 14;
    int r  = t & 16383;
    int j  = r & 7;
    int L  = (r >> 3) & 63;
    int nt = (r >> 9) & 7;
    int ks = r >> 12;
    int l  = g >> 1;
    const float* src = (g & 1) ? (W2s + l * 16384) : (W1s + l * 16384);
    int k = ks * 32 + (L >> 4) * 8 + j;
    int n = nt * 16 + (L & 15);
    wshuf[t] = (bf16_t)src[k * DD + n];
}

__global__ void k_aff_init(float* __restrict__ ss) {
    int f = threadIdx.x;
    if (f < DD) { ss[f] = 1.0f; ss[DD + f] = 0.0f; }
}

__global__ void k_aff_update(const float* __restrict__ stats, const float* __restrict__ gamma,
                             const float* __restrict__ beta, float* __restrict__ scale,
                             float* __restrict__ shift) {
    int f = threadIdx.x;
    if (f < DD) {
        float mu  = stats[f] * (1.0f / N_NODES);
        float var = stats[DD + f] * (1.0f / N_NODES) - mu * mu;
        float inv = rsqrtf(var + BN_EPS);
        float sc  = gamma[f] * inv;
        scale[f] = sc;
        shift[f] = beta[f] - mu * sc;
    }
}

__global__ void k_gbounds(const int* __restrict__ batch, int* __restrict__ gstart) {
    int i = blockIdx.x * blockDim.x + threadIdx.x;
    if (i >= N_NODES) return;
    int b = batch[i];
    int bp = (i == 0) ? -1 : batch[i - 1];
    for (int g = bp + 1; g <= b; ++g) gstart[g] = i;
    if (i == N_NODES - 1)
        for (int g = b + 1; g <= N_GRAPHS; ++g) gstart[g] = N_NODES;
}

// ---------------- fused GIN layer ----------------
// block = 256 (4 waves), 64 nodes. Gather: wave per node; quarter-sub covers 2
// edges/iter (8 total) x 16 feature-lanes. IN_U8: rows are uint8+row-scale
// (128 B line); else bf16 (256 B). Output is ALWAYS uint8+row-scale (relu
// output >= 0 -> full unsigned range); pooling dequantizes.
template<bool IN_U8>
__global__ __launch_bounds__(256, 8) void k_layer(
    const bf16_t* __restrict__ xb,
    const u8* __restrict__ x8, const float* __restrict__ xsc,
    u8* __restrict__ y8, float* __restrict__ ysc,
    const int* __restrict__ poffs, const int* __restrict__ csr,
    const int* __restrict__ deg,
    const float* __restrict__ scale, const float* __restrict__ shift,
    const bf16_t* __restrict__ w1s, const bf16_t* __restrict__ w2s,
    const float* __restrict__ b1, const float* __restrict__ b2,
    float* __restrict__ stats)
{
    __shared__ __align__(16) bf16_t tile[64 * 136];

    const int tid  = threadIdx.x;
    const int w    = tid >> 6;
    const int lane = tid & 63;
    const int base = blockIdx.x * 64;
    const int sub  = lane >> 4;
    const int fl   = lane & 15;

    const uint2* x2 = (const uint2*)x8;   // 16 uint2 per 128 B u8 row
    const uint4* x4 = (const uint4*)xb;   // 16 uint4 per 256 B bf16 row

    // hoisted BN affine for this lane's 8 features
    float sc[8], sh[8];
    {
        const float4* s4 = (const float4*)(scale + fl * 8);
        const float4* h4 = (const float4*)(shift + fl * 8);
        float4 A = s4[0], B = s4[1], C = h4[0], E = h4[1];
        sc[0]=A.x; sc[1]=A.y; sc[2]=A.z; sc[3]=A.w; sc[4]=B.x; sc[5]=B.y; sc[6]=B.z; sc[7]=B.w;
        sh[0]=C.x; sh[1]=C.y; sh[2]=C.z; sh[3]=C.w; sh[4]=E.x; sh[5]=E.y; sh[6]=E.z; sh[7]=E.w;
    }

    // ---- Phase 1: gather + self + BN affine -> tile ----
    for (int r = 0; r < 16; ++r) {
        int row = (w << 4) + r;
        int node = base + row;
        if (node < N_NODES) {
            float a[8] = {0.f, 0.f, 0.f, 0.f, 0.f, 0.f, 0.f, 0.f};
            int e  = poffs[node];
            int eE = poffs[node + 1];
            for (; e < eE; e += 8) {
                int2 ij = *(const int2*)(csr + e + sub * 2);
                if (IN_U8) {
                    uint2 q0 = x2[(size_t)ij.x * 16 + fl];
                    uint2 q1 = x2[(size_t)ij.y * 16 + fl];
                    float s0 = xsc[ij.x];
                    float s1v = xsc[ij.y];
                    acc8u(a, q0, s0);
                    acc8u(a, q1, s1v);
                } else {
                    uint4 r0 = x4[(size_t)ij.x * 16 + fl];
                    uint4 r1 = x4[(size_t)ij.y * 16 + fl];
                    accbf(a, r0);
                    accbf(a, r1);
                }
            }
            // reduce across the 4 quarter-subs
#pragma unroll
            for (int j = 0; j < 8; ++j) a[j] += __shfl_xor(a[j], 32);
#pragma unroll
            for (int j = 0; j < 8; ++j) a[j] += __shfl_xor(a[j], 16);
            // self term (once, post-reduction)
            if (IN_U8) {
                acc8u(a, x2[(size_t)node * 16 + fl], xsc[node]);
            } else {
                accbf(a, x4[(size_t)node * 16 + fl]);
            }
            float cnt = (float)(deg[node] + 1);
            if (lane < 16) {
                bf16x8 pk;
#pragma unroll
                for (int j = 0; j < 8; ++j)
                    pk[j] = (bf16_t)(a[j] * sc[j] + cnt * sh[j]);
                *(bf16x8*)(&tile[row * 136 + fl * 8]) = pk;
            }
        } else if (lane < 16) {
            bf16x8 z;
#pragma unroll
            for (int j = 0; j < 8; ++j) z[j] = (bf16_t)0.f;
            *(bf16x8*)(&tile[row * 136 + fl * 8]) = z;
        }
    }
    __syncthreads();

    // ---- Phase 2: GEMM1 + bias + relu -> tile (reused) ----
    const int q = lane >> 4;
    const int c16 = lane & 15;
    const int arow = (w << 4) + c16;

    bf16x8 afr[4];
#pragma unroll
    for (int ks = 0; ks < 4; ++ks)
        afr[ks] = *(const bf16x8*)(&tile[arow * 136 + ks * 32 + q * 8]);
    __syncthreads();

    f32x4 acc[8];
#pragma unroll
    for (int nt = 0; nt < 8; ++nt) acc[nt] = (f32x4){0.f, 0.f, 0.f, 0.f};
#pragma unroll
    for (int ks = 0; ks < 4; ++ks) {
#pragma unroll
        for (int nt = 0; nt < 8; ++nt) {
            bf16x8 bfr = *(const bf16x8*)(w1s + (((ks << 3) + nt) * 64 + lane) * 8);
            acc[nt] = __builtin_amdgcn_mfma_f32_16x16x32_bf16(afr[ks], bfr, acc[nt], 0, 0, 0);
        }
    }
#pragma unroll
    for (int nt = 0; nt < 8; ++nt) {
        float bias = b1[(nt << 4) + c16];
#pragma unroll
        for (int i = 0; i < 4; ++i) {
            float v = fmaxf(acc[nt][i] + bias, 0.f);
            int row = (w << 4) + (q << 2) + i;
            tile[row * 136 + (nt << 4) + c16] = (bf16_t)v;
        }
    }
    __syncthreads();

    // ---- Phase 3: GEMM2 + bias + relu + BN stats -> tile ----
    bf16x8 afr2[4];
#pragma unroll
    for (int ks = 0; ks < 4; ++ks)
        afr2[ks] = *(const bf16x8*)(&tile[arow * 136 + ks * 32 + q * 8]);
    __syncthreads(); // tile overwritten below

#pragma unroll
    for (int nt = 0; nt < 8; ++nt) acc[nt] = (f32x4){0.f, 0.f, 0.f, 0.f};
#pragma unroll
    for (int ks = 0; ks < 4; ++ks) {
#pragma unroll
        for (int nt = 0; nt < 8; ++nt) {
            bf16x8 bfr = *(const bf16x8*)(w2s + (((ks << 3) + nt) * 64 + lane) * 8);
            acc[nt] = __builtin_amdgcn_mfma_f32_16x16x32_bf16(afr2[ks], bfr, acc[nt], 0, 0, 0);
        }
    }
#pragma unroll
    for (int nt = 0; nt < 8; ++nt) {
        float bias = b2[(nt << 4) + c16];
        float s1 = 0.f, s2 = 0.f;
#pragma unroll
        for (int i = 0; i < 4; ++i) {
            float v = fmaxf(acc[nt][i] + bias, 0.f);
            int row = (w << 4) + (q << 2) + i;
            int node = base + row;
            if (node < N_NODES) {
                s1 += v;
                s2 += v * v;
            }
            tile[row * 136 + (nt << 4) + c16] = (bf16_t)v;
        }
        s1 += __shfl_down(s1, 32); s2 += __shfl_down(s2, 32);
        s1 += __shfl_down(s1, 16); s2 += __shfl_down(s2, 16);
        if (lane < 16) {
            atomicAdd(&stats[(nt << 4) + lane], s1);
            atomicAdd(&stats[DD + (nt << 4) + lane], s2);
        }
    }
    __syncthreads();

    // ---- Phase 4: quantize rows -> uint8 + scale. 4 threads per row. ----
    {
        int row4 = tid >> 2, t4 = tid & 3;
        int node = base + row4;
        if (node < N_NODES) {
            const bf16_t* tp = tile + row4 * 136 + t4 * 32;
            bf16x8 v0 = *(const bf16x8*)(tp);
            bf16x8 v1 = *(const bf16x8*)(tp + 8);
            bf16x8 v2 = *(const bf16x8*)(tp + 16);
            bf16x8 v3 = *(const bf16x8*)(tp + 24);
            float am = 0.f;
#pragma unroll
            for (int k = 0; k < 8; ++k) {
                am = fmaxf(am, (float)v0[k]);
                am = fmaxf(am, (float)v1[k]);
                am = fmaxf(am, (float)v2[k]);
                am = fmaxf(am, (float)v3[k]);
            }
            am = fmaxf(am, __shfl_xor(am, 1));
            am = fmaxf(am, __shfl_xor(am, 2));
            float inv = am > 0.f ? 255.f / am : 0.f;
            if (t4 == 0) ysc[node] = am * (1.f / 255.f);
            u32 u[8];
            u[0] = pack4u((float)v0[0], (float)v0[1], (float)v0[2], (float)v0[3], inv);
            u[1] = pack4u((float)v0[4], (float)v0[5], (float)v0[6], (float)v0[7], inv);
            u[2] = pack4u((float)v1[0], (float)v1[1], (float)v1[2], (float)v1[3], inv);
            u[3] = pack4u((float)v1[4], (float)v1[5], (float)v1[6], (float)v1[7], inv);
            u[4] = pack4u((float)v2[0], (float)v2[1], (float)v2[2], (float)v2[3], inv);
            u[5] = pack4u((float)v2[4], (float)v2[5], (float)v2[6], (float)v2[7], inv);
            u[6] = pack4u((float)v3[0], (float)v3[1], (float)v3[2], (float)v3[3], inv);
            u[7] = pack4u((float)v3[4], (float)v3[5], (float)v3[6], (float)v3[7], inv);
            uint4* yp = (uint4*)(y8 + (size_t)node * DD + t4 * 32);
            yp[0] = make_uint4(u[0], u[1], u[2], u[3]);
            yp[1] = make_uint4(u[4], u[5], u[6], u[7]);
        }
    }
}

// ---------------- pooling + head ----------------

// dequantizing segmented mean-pool over the u8 final-layer output
__global__ __launch_bounds__(128) void k_pool2u(
    const u8* __restrict__ y8, const float* __restrict__ ysc,
    const int* __restrict__ gstart,
    const float* __restrict__ scale, const float* __restrict__ shift,
    float* __restrict__ pooled)
{
    int g = blockIdx.x;
    int t = threadIdx.x;
    int s = gstart[g], e = gstart[g + 1];
    float acc = 0.f;
    for (int n = s; n < e; ++n)
        acc += ysc[n] * (float)y8[(size_t)n * DD + t];
    float cnt = (float)(e - s);
    float v = acc * scale[t] + cnt * shift[t];
    pooled[g * DD + t] = v / fmaxf(cnt, 1.0f);
}

__global__ void k_head(const float* __restrict__ pooled,
                       const float* __restrict__ lin1w, const float* __restrict__ lin1b,
                       const float* __restrict__ lin2w, const float* __restrict__ lin2b,
                       float* __restrict__ out) {
    __shared__ float p[DD];
    __shared__ float h[DD];
    int g = blockIdx.x;
    int t = threadIdx.x;
    p[t] = pooled[g * DD + t];
    __syncthreads();
    float a = lin1b[t];
    for (int k = 0; k < DD; ++k) a += p[k] * lin1w[k * DD + t];
    h[t] = fmaxf(a, 0.f);
    __syncthreads();
    if (t < 10) {
        float o = lin2b[t];
        for (int k = 0; k < DD; ++k) o += h[k] * lin2w[k * 10 + t];
        out[g * 10 + t] = o;
    }
}

// ---------------- launch ----------------

extern "C" void kernel_launch(void* const* d_in, const int* in_sizes, int n_in,
                              void* d_out, int out_size, void* d_ws, size_t ws_size,
                              hipStream_t stream) {
    const float* x      = (const float*)d_in[0];
    const int*   ei     = (const int*)d_in[1];
    const int*   batch  = (const int*)d_in[2];
    const float* W1s    = (const float*)d_in[3];
    const float* b1s    = (const float*)d_in[4];
    const float* W2s    = (const float*)d_in[5];
    const float* b2s    = (const float*)d_in[6];
    const float* gammas = (const float*)d_in[7];
    const float* betas  = (const float*)d_in[8];
    const float* lin1w  = (const float*)d_in[9];
    const float* lin1b  = (const float*)d_in[10];
    const float* lin2w  = (const float*)d_in[11];
    const float* lin2b  = (const float*)d_in[12];
    float* out = (float*)d_out;

    char* p = (char*)d_ws;
    size_t off = 0;
    auto alloc = [&](size_t bytes) -> char* {
        char* r = p + off;
        off += (bytes + 255) & ~(size_t)255;
        return r;
    };
    int*    deg    = (int*)alloc(N_NODES * 4);
    float*  stats  = (float*)alloc(3 * 256 * 4);
    size_t zero_bytes = off;
    int*    poffs  = (int*)alloc((N_NODES + 1) * 4);
    int*    cursor = (int*)alloc(N_NODES * 4);
    int*    csr    = (int*)alloc((N_EDGES + 8 * N_NODES + 16) * 4); // padded capacity
    bf16_t* xb     = (bf16_t*)alloc(((size_t)N_NODES + 1) * DD * 2);
    u8*     q8a    = (u8*)alloc(((size_t)N_NODES + 1) * DD);
    u8*     q8b    = (u8*)alloc(((size_t)N_NODES + 1) * DD);
    float*  sca    = (float*)alloc((N_NODES + 1) * 4);
    float*  scb    = (float*)alloc((N_NODES + 1) * 4);
    bf16_t* wshuf  = (bf16_t*)alloc(6 * 16384 * 2);
    float*  ss     = (float*)alloc(4 * 256 * 4);
    int*    gstart = (int*)alloc((N_GRAPHS + 1) * 4);
    float*  pooled = (float*)alloc(N_GRAPHS * DD * 4);
    if (off > ws_size) return;

    const int* srcA = ei;
    const int* dstA = ei + N_EDGES;

    k_zero<<<256, 256, 0, stream>>>((float4*)d_ws, (int)(zero_bytes / 16));
    k_hist<<<1024, 256, 0, stream>>>(dstA, deg);
    k_scan<<<1, 1024, 0, stream>>>(deg, poffs, cursor);
    k_fill<<<1024, 256, 0, stream>>>(srcA, dstA, cursor, csr);
    k_pad<<<(N_NODES * 8 + 255) / 256, 256, 0, stream>>>(deg, poffs, csr);
    k_cvt<<<1024, 256, 0, stream>>>(x, xb);
    k_zrow<<<1, 128, 0, stream>>>(xb);
    k_zrow8<<<1, 128, 0, stream>>>(q8a, sca);
    k_zrow8<<<1, 128, 0, stream>>>(q8b, scb);
    k_shufw<<<(6 * 16384 + 255) / 256, 256, 0, stream>>>(W1s, W2s, wshuf);
    k_aff_init<<<1, 128, 0, stream>>>(ss);
    k_gbounds<<<(N_NODES + 255) / 256, 256, 0, stream>>>(batch, gstart);

    // L0: xb (bf16) -> q8a. L1: q8a -> q8b. L2: q8b -> q8a (q8a dead after L1).
    k_layer<false><<<NTILES, 256, 0, stream>>>(
        xb, q8a, sca, q8a, sca, poffs, csr, deg,
        ss + 0 * 256, ss + 0 * 256 + 128,
        wshuf + 0 * 16384, wshuf + 1 * 16384,
        b1s + 0 * DD, b2s + 0 * DD, stats + 0 * 256);
    k_aff_update<<<1, 128, 0, stream>>>(stats + 0 * 256, gammas + 0 * DD, betas + 0 * DD,
                                        ss + 1 * 256, ss + 1 * 256 + 128);
    k_layer<true><<<NTILES, 256, 0, stream>>>(
        xb, q8a, sca, q8b, scb, poffs, csr, deg,
        ss + 1 * 256, ss + 1 * 256 + 128,
        wshuf + 2 * 16384, wshuf + 3 * 16384,
        b1s + 1 * DD, b2s + 1 * DD, stats + 1 * 256);
    k_aff_update<<<1, 128, 0, stream>>>(stats + 1 * 256, gammas + 1 * DD, betas + 1 * DD,
                                        ss + 2 * 256, ss + 2 * 256 + 128);
    k_layer<true><<<NTILES, 256, 0, stream>>>(
        xb, q8b, scb, q8a, sca, poffs, csr, deg,
        ss + 2 * 256, ss + 2 * 256 + 128,
        wshuf + 4 * 16384, wshuf + 5 * 16384,
        b1s + 2 * DD, b2s + 2 * DD, stats + 2 * 256);
    k_aff_update<<<1, 128, 0, stream>>>(stats + 2 * 256, gammas + 2 * DD, betas + 2 * DD,
                                        ss + 3 * 256, ss + 3 * 256 + 128);

    k_pool2u<<<N_GRAPHS, 128, 0, stream>>>(q8a, sca, gstart,
                                           ss + 3 * 256, ss + 3 * 256 + 128, pooled);
    k_head<<<N_GRAPHS, 128, 0, stream>>>(pooled, lin1w, lin1b, lin2w, lin2b, out);
}